// Round 9
// baseline (380.541 us; speedup 1.0000x reference)
//
#include <hip/hip_runtime.h>

// CurvatureLoss3D — R9: identical to R8 (no-LDS register-sliding packed
// stencil) except __launch_bounds__(256, 6). Evidence R4-R8: OccupancyPercent
// tracked the waves-per-eu arg (4 -> ~32%, 3 -> ~22%) while VGPR (60-76)
// allowed 7 waves/SIMD — the arg appears to gate residency, not just cap RA.
// 6 waves/EU -> RA cap ~85 VGPR (we use 72, no spill) and residency cap >=
// available blocks/CU (5.34), so all 1368 blocks co-resident.

typedef float v2f __attribute__((ext_vector_type(2)));

constexpr int DIM  = 192;
constexpr int ODIM = 190;
constexpr int TX = 32, TY = 32, CZ = 10;
constexpr int NTX = 6, NTY = 6, NTZ = 19;     // 19*10 = 190 exactly
constexpr int PLANE = DIM * DIM;
constexpr int NBLOCKS = 2 * NTZ * NTY * NTX;  // 1368

struct Slice {
    v2f   q[3][4];          // rows y..y+2; q[dy][k] = (r[k], r[k+2])
    float mn[6], mx[6];     // per-column min/max over the 3 rows
};

__global__ __launch_bounds__(256, 6) void curv_main(const float* __restrict__ phi,
                                                    double* __restrict__ acc,
                                                    int use_partials) {
    int bx = blockIdx.x;
    const int tx = bx % NTX; bx /= NTX;
    const int ty = bx % NTY; bx /= NTY;
    const int tz = bx % NTZ; bx /= NTZ;
    const int n  = bx;

    const int xbase = tx * TX, ybase = ty * TY, zbase = tz * CZ;
    const int tid = threadIdx.x;
    const int row = tid >> 3;          // output y within tile (0..31)
    const int x0  = (tid & 7) * 4;     // output x within tile (0..28)
    const float* pn = phi + (long long)n * DIM * PLANE;

    // hoisted addresses
    const int c4 = xbase + x0;                       // <= 188: float4 in-bounds
    int c2t = c4 + 4; if (c2t > DIM - 2) c2t = DIM - 2;   // clamp: cols <= 191
    const int c2 = c2t;
    int yoff[3];
#pragma unroll
    for (int dy = 0; dy < 3; ++dy) {
        int iy = ybase + row + dy; if (iy > DIM - 1) iy = DIM - 1;
        yoff[dy] = iy * DIM;
    }

    float4 t4[3]; float2 t2[3];
    auto pref = [&](int g) {            // global -> tmp regs, stays in flight
        int gz = zbase + g; if (gz > DIM - 1) gz = DIM - 1;
        const float* base = pn + gz * PLANE;
#pragma unroll
        for (int dy = 0; dy < 3; ++dy) {
            t4[dy] = *(const float4*)(base + yoff[dy] + c4);
            t2[dy] = *(const float2*)(base + yoff[dy] + c2);
        }
    };

    auto unpack = [&](Slice& s) {       // tmp regs -> packed slice (+min/max)
#pragma unroll
        for (int dy = 0; dy < 3; ++dy) {
            const float4 a = t4[dy]; const float2 b = t2[dy];
            s.q[dy][0] = (v2f){a.x, a.z};
            s.q[dy][1] = (v2f){a.y, a.w};
            s.q[dy][2] = (v2f){a.z, b.x};
            s.q[dy][3] = (v2f){a.w, b.y};
            if (dy == 0) {
                s.mn[0] = a.x; s.mn[1] = a.y; s.mn[2] = a.z;
                s.mn[3] = a.w; s.mn[4] = b.x; s.mn[5] = b.y;
                s.mx[0] = a.x; s.mx[1] = a.y; s.mx[2] = a.z;
                s.mx[3] = a.w; s.mx[4] = b.x; s.mx[5] = b.y;
            } else {
                s.mn[0] = fminf(s.mn[0], a.x); s.mx[0] = fmaxf(s.mx[0], a.x);
                s.mn[1] = fminf(s.mn[1], a.y); s.mx[1] = fmaxf(s.mx[1], a.y);
                s.mn[2] = fminf(s.mn[2], a.z); s.mx[2] = fmaxf(s.mx[2], a.z);
                s.mn[3] = fminf(s.mn[3], a.w); s.mx[3] = fmaxf(s.mx[3], a.w);
                s.mn[4] = fminf(s.mn[4], b.x); s.mx[4] = fmaxf(s.mx[4], b.x);
                s.mn[5] = fminf(s.mn[5], b.y); s.mx[5] = fmaxf(s.mx[5], b.y);
            }
        }
    };

    double sp = 0.0, sc = 0.0;
    const float EPSF = 1e-8f;
    const int oy = ybase + row;

    bool vmask[4];
#pragma unroll
    for (int j = 0; j < 4; ++j)
        vmask[j] = (oy < ODIM) && (xbase + x0 + j < ODIM);

    auto compute = [&](const Slice& s0, const Slice& s1, const Slice& s2, int zo) {
        float colmn[6], colmx[6];
#pragma unroll
        for (int c = 0; c < 6; ++c) {
            colmn[c] = fminf(fminf(s0.mn[c], s1.mn[c]), s2.mn[c]);
            colmx[c] = fmaxf(fmaxf(s0.mx[c], s1.mx[c]), s2.mx[c]);
        }

        float fsp = 0.0f, fsc = 0.0f;
#pragma unroll
        for (int p = 0; p < 2; ++p) {
            v2f gx = 0.5f * (s2.q[1][p + 1] - s0.q[1][p + 1]);
            v2f gy = 0.5f * (s1.q[2][p + 1] - s1.q[0][p + 1]);
            v2f gz = 0.5f * (s1.q[1][p + 2] - s1.q[1][p]);

            v2f c2v = 2.0f * s1.q[1][p + 1];
            v2f hxx = s0.q[1][p + 1] - c2v + s2.q[1][p + 1];
            v2f hyy = s1.q[0][p + 1] - c2v + s1.q[2][p + 1];
            v2f hzz = s1.q[1][p] - c2v + s1.q[1][p + 2];

            v2f hxy = 0.25f * (s0.q[0][p + 1] - s0.q[2][p + 1]
                             - s2.q[0][p + 1] + s2.q[2][p + 1]);
            v2f hxz = 0.25f * (s0.q[1][p] - s0.q[1][p + 2]
                             - s2.q[1][p] + s2.q[1][p + 2]);
            v2f hyz = 0.25f * (s1.q[0][p] - s1.q[0][p + 2]
                             - s1.q[2][p] + s1.q[2][p + 2]);

            v2f gx2 = gx * gx, gy2 = gy * gy, gz2 = gz * gz;
            v2f mag2 = gx2 + gy2 + gz2 + EPSF;

            v2f inv1 = (v2f){ __builtin_amdgcn_rsqf(mag2.x),
                              __builtin_amdgcn_rsqf(mag2.y) };
            v2f inv3 = inv1 * inv1 * inv1;

            v2f cross = gx * gy * hxy + gx * gz * hxz + gy * gz * hyz;

            v2f mean_c = (gx2 * (hyy + hzz) + gy2 * (hxx + hzz) +
                          gz2 * (hxx + hyy) - 2.0f * cross) * inv3;
            v2f lap   = (hxx + hyy + hzz) * inv1;
            v2f quad  = (gx2 * hxx + gy2 * hyy + gz2 * hzz + 2.0f * cross) * inv3;
            v2f gauss = lap - quad;

            v2f disc = mean_c * mean_c - gauss;
            v2f sq = (v2f){ sqrtf(fabsf(disc.x) + EPSF),
                            sqrtf(fabsf(disc.y) + EPSF) };
            v2f k1 = mean_c + sq;
            v2f t  = 2.0f * k1;              // k1 / (0.5+1e-8) == 2*k1 in f32
            v2f pen2 = t * t - 1.0f;

#pragma unroll
            for (int e = 0; e < 2; ++e) {
                const int j = p + 2 * e;
                float pen = fmaxf(e ? pen2.y : pen2.x, 0.0f);
                float mn = fminf(fminf(colmn[j], colmn[j + 1]), colmn[j + 2]);
                float mx = fmaxf(fmaxf(colmx[j], colmx[j + 1]), colmx[j + 2]);
                if (vmask[j] && (mn * mx < 0.0f)) {
                    fsp += pen;
                    fsc += 1.0f;
                }
            }
        }
        sp += (double)fsp;
        sc += (double)fsc;
    };

    Slice s0, s1, s2;

    // ---- prologue: planes 0,1 unpacked; plane 2 in flight ----
    pref(0); unpack(s0);
    pref(1); unpack(s1);
    pref(2);

    // ---- 10 pipelined phases: unpack plane z+2, prefetch z+3, compute z ----
    unpack(s2); pref(3);  compute(s0, s1, s2, 0);
    unpack(s0); pref(4);  compute(s1, s2, s0, 1);
    unpack(s1); pref(5);  compute(s2, s0, s1, 2);
    unpack(s2); pref(6);  compute(s0, s1, s2, 3);
    unpack(s0); pref(7);  compute(s1, s2, s0, 4);
    unpack(s1); pref(8);  compute(s2, s0, s1, 5);
    unpack(s2); pref(9);  compute(s0, s1, s2, 6);
    unpack(s0); pref(10); compute(s1, s2, s0, 7);
    unpack(s1); pref(11); compute(s2, s0, s1, 8);
    unpack(s2);           compute(s0, s1, s2, 9);

    // ---- reduction ----
#pragma unroll
    for (int off = 32; off > 0; off >>= 1) {
        sp += __shfl_down(sp, off, 64);
        sc += __shfl_down(sc, off, 64);
    }

    __shared__ double lsp[4], lsc[4];
    const int wave = tid >> 6, lane = tid & 63;
    if (lane == 0) { lsp[wave] = sp; lsc[wave] = sc; }
    __syncthreads();
    if (tid == 0) {
        double tp = lsp[0] + lsp[1] + lsp[2] + lsp[3];
        double tc = lsc[0] + lsc[1] + lsc[2] + lsc[3];
        if (use_partials) {
            acc[2 * blockIdx.x]     = tp;
            acc[2 * blockIdx.x + 1] = tc;
        } else {
            atomicAdd(&acc[0], tp);
            atomicAdd(&acc[1], tc);
        }
    }
}

__global__ __launch_bounds__(256) void curv_reduce(const double* __restrict__ part,
                                                   int nblocks, int use_partials,
                                                   float* __restrict__ out) {
    double sp = 0.0, sc = 0.0;
    if (use_partials) {
        for (int i = threadIdx.x; i < nblocks; i += 256) {
            sp += part[2 * i];
            sc += part[2 * i + 1];
        }
    } else if (threadIdx.x == 0) {
        sp = part[0]; sc = part[1];
    }
#pragma unroll
    for (int off = 32; off > 0; off >>= 1) {
        sp += __shfl_down(sp, off, 64);
        sc += __shfl_down(sc, off, 64);
    }
    __shared__ double lsp[4], lsc[4];
    const int wave = threadIdx.x >> 6, lane = threadIdx.x & 63;
    if (lane == 0) { lsp[wave] = sp; lsc[wave] = sc; }
    __syncthreads();
    if (threadIdx.x == 0) {
        double tp = lsp[0] + lsp[1] + lsp[2] + lsp[3];
        double tc = lsc[0] + lsc[1] + lsc[2] + lsc[3];
        out[0] = (float)(tp / (tc + 1e-8));
    }
}

extern "C" void kernel_launch(void* const* d_in, const int* in_sizes, int n_in,
                              void* d_out, int out_size, void* d_ws, size_t ws_size,
                              hipStream_t stream) {
    const float* phi = (const float*)d_in[0];
    float* out = (float*)d_out;
    double* acc = (double*)d_ws;

    const int use_partials = (ws_size >= (size_t)(2 * NBLOCKS) * sizeof(double)) ? 1 : 0;
    if (!use_partials) {
        hipMemsetAsync(d_ws, 0, 2 * sizeof(double), stream);
    }

    curv_main<<<NBLOCKS, 256, 0, stream>>>(phi, acc, use_partials);
    curv_reduce<<<1, 256, 0, stream>>>(acc, NBLOCKS, use_partials, out);
}

// Round 10
// 109.221 us; speedup vs baseline: 3.4841x; 3.4841x over previous
//
#include <hip/hip_runtime.h>

// CurvatureLoss3D — R10: R8 body (no-LDS register-sliding packed stencil),
// plain __launch_bounds__(256). Evidence R5/R9: the min-waves-per-EU arg's
// RA cap quantizes unpredictably (4 -> 128 VGPR, 6 -> 40 VGPR) and both
// mis-set directions spill; R9 proved the arg also gates residency (occ
// 22 -> 56%). Dropping the arg lets RA fit the ~76-VGPR working set and
// lets HW set residency from actual usage (512/76 -> up to 6 waves/SIMD).

typedef float v2f __attribute__((ext_vector_type(2)));

constexpr int DIM  = 192;
constexpr int ODIM = 190;
constexpr int TX = 32, TY = 32, CZ = 10;
constexpr int NTX = 6, NTY = 6, NTZ = 19;     // 19*10 = 190 exactly
constexpr int PLANE = DIM * DIM;
constexpr int NBLOCKS = 2 * NTZ * NTY * NTX;  // 1368

struct Slice {
    v2f   q[3][4];          // rows y..y+2; q[dy][k] = (r[k], r[k+2])
    float mn[6], mx[6];     // per-column min/max over the 3 rows
};

__global__ __launch_bounds__(256) void curv_main(const float* __restrict__ phi,
                                                 double* __restrict__ acc,
                                                 int use_partials) {
    int bx = blockIdx.x;
    const int tx = bx % NTX; bx /= NTX;
    const int ty = bx % NTY; bx /= NTY;
    const int tz = bx % NTZ; bx /= NTZ;
    const int n  = bx;

    const int xbase = tx * TX, ybase = ty * TY, zbase = tz * CZ;
    const int tid = threadIdx.x;
    const int row = tid >> 3;          // output y within tile (0..31)
    const int x0  = (tid & 7) * 4;     // output x within tile (0..28)
    const float* pn = phi + (long long)n * DIM * PLANE;

    // hoisted addresses
    const int c4 = xbase + x0;                       // <= 188: float4 in-bounds
    int c2t = c4 + 4; if (c2t > DIM - 2) c2t = DIM - 2;   // clamp: cols <= 191
    const int c2 = c2t;
    int yoff[3];
#pragma unroll
    for (int dy = 0; dy < 3; ++dy) {
        int iy = ybase + row + dy; if (iy > DIM - 1) iy = DIM - 1;
        yoff[dy] = iy * DIM;
    }

    float4 t4[3]; float2 t2[3];
    auto pref = [&](int g) {            // global -> tmp regs, stays in flight
        int gz = zbase + g; if (gz > DIM - 1) gz = DIM - 1;
        const float* base = pn + gz * PLANE;
#pragma unroll
        for (int dy = 0; dy < 3; ++dy) {
            t4[dy] = *(const float4*)(base + yoff[dy] + c4);
            t2[dy] = *(const float2*)(base + yoff[dy] + c2);
        }
    };

    auto unpack = [&](Slice& s) {       // tmp regs -> packed slice (+min/max)
#pragma unroll
        for (int dy = 0; dy < 3; ++dy) {
            const float4 a = t4[dy]; const float2 b = t2[dy];
            s.q[dy][0] = (v2f){a.x, a.z};
            s.q[dy][1] = (v2f){a.y, a.w};
            s.q[dy][2] = (v2f){a.z, b.x};
            s.q[dy][3] = (v2f){a.w, b.y};
            if (dy == 0) {
                s.mn[0] = a.x; s.mn[1] = a.y; s.mn[2] = a.z;
                s.mn[3] = a.w; s.mn[4] = b.x; s.mn[5] = b.y;
                s.mx[0] = a.x; s.mx[1] = a.y; s.mx[2] = a.z;
                s.mx[3] = a.w; s.mx[4] = b.x; s.mx[5] = b.y;
            } else {
                s.mn[0] = fminf(s.mn[0], a.x); s.mx[0] = fmaxf(s.mx[0], a.x);
                s.mn[1] = fminf(s.mn[1], a.y); s.mx[1] = fmaxf(s.mx[1], a.y);
                s.mn[2] = fminf(s.mn[2], a.z); s.mx[2] = fmaxf(s.mx[2], a.z);
                s.mn[3] = fminf(s.mn[3], a.w); s.mx[3] = fmaxf(s.mx[3], a.w);
                s.mn[4] = fminf(s.mn[4], b.x); s.mx[4] = fmaxf(s.mx[4], b.x);
                s.mn[5] = fminf(s.mn[5], b.y); s.mx[5] = fmaxf(s.mx[5], b.y);
            }
        }
    };

    double sp = 0.0, sc = 0.0;
    const float EPSF = 1e-8f;
    const int oy = ybase + row;

    bool vmask[4];
#pragma unroll
    for (int j = 0; j < 4; ++j)
        vmask[j] = (oy < ODIM) && (xbase + x0 + j < ODIM);

    auto compute = [&](const Slice& s0, const Slice& s1, const Slice& s2) {
        float colmn[6], colmx[6];
#pragma unroll
        for (int c = 0; c < 6; ++c) {
            colmn[c] = fminf(fminf(s0.mn[c], s1.mn[c]), s2.mn[c]);
            colmx[c] = fmaxf(fmaxf(s0.mx[c], s1.mx[c]), s2.mx[c]);
        }

        float fsp = 0.0f, fsc = 0.0f;
#pragma unroll
        for (int p = 0; p < 2; ++p) {
            v2f gx = 0.5f * (s2.q[1][p + 1] - s0.q[1][p + 1]);
            v2f gy = 0.5f * (s1.q[2][p + 1] - s1.q[0][p + 1]);
            v2f gz = 0.5f * (s1.q[1][p + 2] - s1.q[1][p]);

            v2f c2v = 2.0f * s1.q[1][p + 1];
            v2f hxx = s0.q[1][p + 1] - c2v + s2.q[1][p + 1];
            v2f hyy = s1.q[0][p + 1] - c2v + s1.q[2][p + 1];
            v2f hzz = s1.q[1][p] - c2v + s1.q[1][p + 2];

            v2f hxy = 0.25f * (s0.q[0][p + 1] - s0.q[2][p + 1]
                             - s2.q[0][p + 1] + s2.q[2][p + 1]);
            v2f hxz = 0.25f * (s0.q[1][p] - s0.q[1][p + 2]
                             - s2.q[1][p] + s2.q[1][p + 2]);
            v2f hyz = 0.25f * (s1.q[0][p] - s1.q[0][p + 2]
                             - s1.q[2][p] + s1.q[2][p + 2]);

            v2f gx2 = gx * gx, gy2 = gy * gy, gz2 = gz * gz;
            v2f mag2 = gx2 + gy2 + gz2 + EPSF;

            v2f inv1 = (v2f){ __builtin_amdgcn_rsqf(mag2.x),
                              __builtin_amdgcn_rsqf(mag2.y) };
            v2f inv3 = inv1 * inv1 * inv1;

            v2f cross = gx * gy * hxy + gx * gz * hxz + gy * gz * hyz;

            v2f mean_c = (gx2 * (hyy + hzz) + gy2 * (hxx + hzz) +
                          gz2 * (hxx + hyy) - 2.0f * cross) * inv3;
            v2f lap   = (hxx + hyy + hzz) * inv1;
            v2f quad  = (gx2 * hxx + gy2 * hyy + gz2 * hzz + 2.0f * cross) * inv3;
            v2f gauss = lap - quad;

            v2f disc = mean_c * mean_c - gauss;
            v2f sq = (v2f){ sqrtf(fabsf(disc.x) + EPSF),
                            sqrtf(fabsf(disc.y) + EPSF) };
            v2f k1 = mean_c + sq;
            v2f t  = 2.0f * k1;              // k1 / (0.5+1e-8) == 2*k1 in f32
            v2f pen2 = t * t - 1.0f;

#pragma unroll
            for (int e = 0; e < 2; ++e) {
                const int j = p + 2 * e;
                float pen = fmaxf(e ? pen2.y : pen2.x, 0.0f);
                float mn = fminf(fminf(colmn[j], colmn[j + 1]), colmn[j + 2]);
                float mx = fmaxf(fmaxf(colmx[j], colmx[j + 1]), colmx[j + 2]);
                if (vmask[j] && (mn * mx < 0.0f)) {
                    fsp += pen;
                    fsc += 1.0f;
                }
            }
        }
        sp += (double)fsp;
        sc += (double)fsc;
    };

    Slice s0, s1, s2;

    // ---- prologue: planes 0,1 unpacked; plane 2 in flight ----
    pref(0); unpack(s0);
    pref(1); unpack(s1);
    pref(2);

    // ---- 10 pipelined phases: unpack plane z+2, prefetch z+3, compute z ----
    unpack(s2); pref(3);  compute(s0, s1, s2);
    unpack(s0); pref(4);  compute(s1, s2, s0);
    unpack(s1); pref(5);  compute(s2, s0, s1);
    unpack(s2); pref(6);  compute(s0, s1, s2);
    unpack(s0); pref(7);  compute(s1, s2, s0);
    unpack(s1); pref(8);  compute(s2, s0, s1);
    unpack(s2); pref(9);  compute(s0, s1, s2);
    unpack(s0); pref(10); compute(s1, s2, s0);
    unpack(s1); pref(11); compute(s2, s0, s1);
    unpack(s2);           compute(s0, s1, s2);

    // ---- reduction ----
#pragma unroll
    for (int off = 32; off > 0; off >>= 1) {
        sp += __shfl_down(sp, off, 64);
        sc += __shfl_down(sc, off, 64);
    }

    __shared__ double lsp[4], lsc[4];
    const int wave = tid >> 6, lane = tid & 63;
    if (lane == 0) { lsp[wave] = sp; lsc[wave] = sc; }
    __syncthreads();
    if (tid == 0) {
        double tp = lsp[0] + lsp[1] + lsp[2] + lsp[3];
        double tc = lsc[0] + lsc[1] + lsc[2] + lsc[3];
        if (use_partials) {
            acc[2 * blockIdx.x]     = tp;
            acc[2 * blockIdx.x + 1] = tc;
        } else {
            atomicAdd(&acc[0], tp);
            atomicAdd(&acc[1], tc);
        }
    }
}

__global__ __launch_bounds__(256) void curv_reduce(const double* __restrict__ part,
                                                   int nblocks, int use_partials,
                                                   float* __restrict__ out) {
    double sp = 0.0, sc = 0.0;
    if (use_partials) {
        for (int i = threadIdx.x; i < nblocks; i += 256) {
            sp += part[2 * i];
            sc += part[2 * i + 1];
        }
    } else if (threadIdx.x == 0) {
        sp = part[0]; sc = part[1];
    }
#pragma unroll
    for (int off = 32; off > 0; off >>= 1) {
        sp += __shfl_down(sp, off, 64);
        sc += __shfl_down(sc, off, 64);
    }
    __shared__ double lsp[4], lsc[4];
    const int wave = threadIdx.x >> 6, lane = threadIdx.x & 63;
    if (lane == 0) { lsp[wave] = sp; lsc[wave] = sc; }
    __syncthreads();
    if (threadIdx.x == 0) {
        double tp = lsp[0] + lsp[1] + lsp[2] + lsp[3];
        double tc = lsc[0] + lsc[1] + lsc[2] + lsc[3];
        out[0] = (float)(tp / (tc + 1e-8));
    }
}

extern "C" void kernel_launch(void* const* d_in, const int* in_sizes, int n_in,
                              void* d_out, int out_size, void* d_ws, size_t ws_size,
                              hipStream_t stream) {
    const float* phi = (const float*)d_in[0];
    float* out = (float*)d_out;
    double* acc = (double*)d_ws;

    const int use_partials = (ws_size >= (size_t)(2 * NBLOCKS) * sizeof(double)) ? 1 : 0;
    if (!use_partials) {
        hipMemsetAsync(d_ws, 0, 2 * sizeof(double), stream);
    }

    curv_main<<<NBLOCKS, 256, 0, stream>>>(phi, acc, use_partials);
    curv_reduce<<<1, 256, 0, stream>>>(acc, NBLOCKS, use_partials, out);
}

// Round 11
// 105.671 us; speedup vs baseline: 3.6012x; 1.0336x over previous
//
#include <hip/hip_runtime.h>

// CurvatureLoss3D — R11: R8 structure frozen ((256,3), packed no-LDS
// register-sliding), three issue/overhead cuts:
//  1. CZ=19/NTZ=10 -> 720 blocks = 2.8/CU: ONE dispatch round at the
//     (256,3) residency cap of 3 blocks/CU (R8's 1368 blocks ran 1.78
//     rounds, round 2 only 44% full). Staging 210 vs 228 planes.
//  2. Power-of-2 constant folding: raw differences G=2g, M=4h_mixed;
//     mean_c = (SumG^2(h+h) - 0.5 crossG) * 2r^3 with r = rsq(G^2+4eps).
//     All rescalings are exact powers of two -> bit-identical results.
//  3. Slice-level x-collapse of min/max (amortized once per plane) and
//     float thread-level accumulators (f64 only at the final reduction).

typedef float v2f __attribute__((ext_vector_type(2)));

constexpr int DIM  = 192;
constexpr int ODIM = 190;
constexpr int TX = 32, TY = 32, CZ = 19;
constexpr int NTX = 6, NTY = 6, NTZ = 10;     // 10*19 = 190 exactly
constexpr int PLANE = DIM * DIM;
constexpr int NBLOCKS = 2 * NTZ * NTY * NTX;  // 720 = 2.8 blocks/CU

struct Slice {
    v2f   q[3][4];          // rows y..y+2; q[dy][k] = (r[k], r[k+2])
    float xmn[4], xmx[4];   // per-voxel-window (3 rows x 3 cols) min/max, this plane
};

__global__ __launch_bounds__(256, 3) void curv_main(const float* __restrict__ phi,
                                                    double* __restrict__ acc,
                                                    int use_partials) {
    int bx = blockIdx.x;
    const int tx = bx % NTX; bx /= NTX;
    const int ty = bx % NTY; bx /= NTY;
    const int tz = bx % NTZ; bx /= NTZ;
    const int n  = bx;

    const int xbase = tx * TX, ybase = ty * TY, zbase = tz * CZ;
    const int tid = threadIdx.x;
    const int row = tid >> 3;          // output y within tile (0..31)
    const int x0  = (tid & 7) * 4;     // output x within tile (0..28)
    const float* pn = phi + (long long)n * DIM * PLANE;

    // hoisted addresses (zbase+g <= 171+20 = 191: no z clamp needed)
    const int c4 = xbase + x0;                       // <= 188: float4 in-bounds
    int c2t = c4 + 4; if (c2t > DIM - 2) c2t = DIM - 2;
    const int c2 = c2t;
    int yoff[3];
#pragma unroll
    for (int dy = 0; dy < 3; ++dy) {
        int iy = ybase + row + dy; if (iy > DIM - 1) iy = DIM - 1;
        yoff[dy] = iy * DIM;
    }

    float4 t4[3]; float2 t2[3];
    auto pref = [&](int g) {            // global -> tmp regs, stays in flight
        const float* base = pn + (zbase + g) * PLANE;
#pragma unroll
        for (int dy = 0; dy < 3; ++dy) {
            t4[dy] = *(const float4*)(base + yoff[dy] + c4);
            t2[dy] = *(const float2*)(base + yoff[dy] + c2);
        }
    };

    auto unpack = [&](Slice& s) {       // tmp regs -> packed slice (+window minmax)
        float mn6[6], mx6[6];
#pragma unroll
        for (int dy = 0; dy < 3; ++dy) {
            const float4 a = t4[dy]; const float2 b = t2[dy];
            s.q[dy][0] = (v2f){a.x, a.z};
            s.q[dy][1] = (v2f){a.y, a.w};
            s.q[dy][2] = (v2f){a.z, b.x};
            s.q[dy][3] = (v2f){a.w, b.y};
            if (dy == 0) {
                mn6[0] = a.x; mn6[1] = a.y; mn6[2] = a.z;
                mn6[3] = a.w; mn6[4] = b.x; mn6[5] = b.y;
                mx6[0] = a.x; mx6[1] = a.y; mx6[2] = a.z;
                mx6[3] = a.w; mx6[4] = b.x; mx6[5] = b.y;
            } else {
                mn6[0] = fminf(mn6[0], a.x); mx6[0] = fmaxf(mx6[0], a.x);
                mn6[1] = fminf(mn6[1], a.y); mx6[1] = fmaxf(mx6[1], a.y);
                mn6[2] = fminf(mn6[2], a.z); mx6[2] = fmaxf(mx6[2], a.z);
                mn6[3] = fminf(mn6[3], a.w); mx6[3] = fmaxf(mx6[3], a.w);
                mn6[4] = fminf(mn6[4], b.x); mx6[4] = fmaxf(mx6[4], b.x);
                mn6[5] = fminf(mn6[5], b.y); mx6[5] = fmaxf(mx6[5], b.y);
            }
        }
#pragma unroll
        for (int j = 0; j < 4; ++j) {   // x-collapse: per-voxel 3x3 window, this plane
            s.xmn[j] = fminf(fminf(mn6[j], mn6[j + 1]), mn6[j + 2]);
            s.xmx[j] = fmaxf(fmaxf(mx6[j], mx6[j + 1]), mx6[j + 2]);
        }
    };

    float fsp = 0.0f, fsc = 0.0f;
    const float EPSF = 1e-8f;
    const float EPS4 = 4e-8f;           // 4*eps (exact: eps scaled by 2^2)
    const int oy = ybase + row;

    bool vmask[4];
#pragma unroll
    for (int j = 0; j < 4; ++j)
        vmask[j] = (oy < ODIM) && (xbase + x0 + j < ODIM);

    auto compute = [&](const Slice& s0, const Slice& s1, const Slice& s2) {
        float wmn[4], wmx[4];
#pragma unroll
        for (int j = 0; j < 4; ++j) {
            wmn[j] = fminf(fminf(s0.xmn[j], s1.xmn[j]), s2.xmn[j]);
            wmx[j] = fmaxf(fmaxf(s0.xmx[j], s1.xmx[j]), s2.xmx[j]);
        }

#pragma unroll
        for (int p = 0; p < 2; ++p) {
            // raw differences: G = 2g, M = 4h_mixed (constants folded, exact)
            v2f Gx = s2.q[1][p + 1] - s0.q[1][p + 1];
            v2f Gy = s1.q[2][p + 1] - s1.q[0][p + 1];
            v2f Gz = s1.q[1][p + 2] - s1.q[1][p];

            v2f c2v = 2.0f * s1.q[1][p + 1];
            v2f hxx = s0.q[1][p + 1] - c2v + s2.q[1][p + 1];
            v2f hyy = s1.q[0][p + 1] - c2v + s1.q[2][p + 1];
            v2f hzz = s1.q[1][p] - c2v + s1.q[1][p + 2];

            v2f Mxy = s0.q[0][p + 1] - s0.q[2][p + 1]
                    - s2.q[0][p + 1] + s2.q[2][p + 1];
            v2f Mxz = s0.q[1][p] - s0.q[1][p + 2]
                    - s2.q[1][p] + s2.q[1][p + 2];
            v2f Myz = s1.q[0][p] - s1.q[0][p + 2]
                    - s1.q[2][p] + s1.q[2][p + 2];

            v2f Gx2 = Gx * Gx, Gy2 = Gy * Gy, Gz2 = Gz * Gz;
            v2f mag2G = Gx2 + Gy2 + Gz2 + EPS4;      // = 4*(mag2)

            v2f r = (v2f){ __builtin_amdgcn_rsqf(mag2G.x),
                           __builtin_amdgcn_rsqf(mag2G.y) };   // = inv1/2 exactly
            v2f r3 = r * r * r;                       // = inv3/8
            v2f twor3 = r3 + r3;                      // = inv3/4

            v2f crossG = Gx * Gy * Mxy + Gx * Gz * Mxz + Gy * Gz * Myz; // 16*cross

            v2f num1 = Gx2 * (hyy + hzz) + Gy2 * (hxx + hzz) +
                       Gz2 * (hxx + hyy) - 0.5f * crossG;      // 4*num_orig
            v2f mean_c = num1 * twor3;                // bit-exact vs original
            v2f lap   = (hxx + hyy + hzz) * (r + r);
            v2f num2  = Gx2 * hxx + Gy2 * hyy + Gz2 * hzz + 0.5f * crossG;
            v2f quad  = num2 * twor3;
            v2f gauss = lap - quad;

            v2f disc = mean_c * mean_c - gauss;
            v2f sq = (v2f){ sqrtf(fabsf(disc.x) + EPSF),
                            sqrtf(fabsf(disc.y) + EPSF) };
            v2f k1 = mean_c + sq;
            v2f t  = 2.0f * k1;                       // k1/(0.5+1e-8) == 2*k1
            v2f pen2 = t * t - 1.0f;

#pragma unroll
            for (int e = 0; e < 2; ++e) {
                const int j = p + 2 * e;
                float pen = fmaxf(e ? pen2.y : pen2.x, 0.0f);
                if (vmask[j] && (wmn[j] * wmx[j] < 0.0f)) {
                    fsp += pen;
                    fsc += 1.0f;
                }
            }
        }
    };

    Slice s0, s1, s2;

    // ---- prologue: planes 0,1 unpacked; plane 2 in flight ----
    pref(0); unpack(s0);
    pref(1); unpack(s1);
    pref(2);

    // ---- 19 pipelined phases: unpack plane z+2, prefetch z+3, compute z ----
    unpack(s2); pref(3);  compute(s0, s1, s2);   // z = 0
    unpack(s0); pref(4);  compute(s1, s2, s0);
    unpack(s1); pref(5);  compute(s2, s0, s1);
    unpack(s2); pref(6);  compute(s0, s1, s2);
    unpack(s0); pref(7);  compute(s1, s2, s0);
    unpack(s1); pref(8);  compute(s2, s0, s1);
    unpack(s2); pref(9);  compute(s0, s1, s2);
    unpack(s0); pref(10); compute(s1, s2, s0);
    unpack(s1); pref(11); compute(s2, s0, s1);
    unpack(s2); pref(12); compute(s0, s1, s2);
    unpack(s0); pref(13); compute(s1, s2, s0);
    unpack(s1); pref(14); compute(s2, s0, s1);
    unpack(s2); pref(15); compute(s0, s1, s2);
    unpack(s0); pref(16); compute(s1, s2, s0);
    unpack(s1); pref(17); compute(s2, s0, s1);
    unpack(s2); pref(18); compute(s0, s1, s2);
    unpack(s0); pref(19); compute(s1, s2, s0);
    unpack(s1); pref(20); compute(s2, s0, s1);
    unpack(s2);           compute(s0, s1, s2);   // z = 18

    // ---- reduction (double from here) ----
    double sp = (double)fsp, sc = (double)fsc;
#pragma unroll
    for (int off = 32; off > 0; off >>= 1) {
        sp += __shfl_down(sp, off, 64);
        sc += __shfl_down(sc, off, 64);
    }

    __shared__ double lsp[4], lsc[4];
    const int wave = tid >> 6, lane = tid & 63;
    if (lane == 0) { lsp[wave] = sp; lsc[wave] = sc; }
    __syncthreads();
    if (tid == 0) {
        double tp = lsp[0] + lsp[1] + lsp[2] + lsp[3];
        double tc = lsc[0] + lsc[1] + lsc[2] + lsc[3];
        if (use_partials) {
            acc[2 * blockIdx.x]     = tp;
            acc[2 * blockIdx.x + 1] = tc;
        } else {
            atomicAdd(&acc[0], tp);
            atomicAdd(&acc[1], tc);
        }
    }
}

__global__ __launch_bounds__(256) void curv_reduce(const double* __restrict__ part,
                                                   int nblocks, int use_partials,
                                                   float* __restrict__ out) {
    double sp = 0.0, sc = 0.0;
    if (use_partials) {
        for (int i = threadIdx.x; i < nblocks; i += 256) {
            sp += part[2 * i];
            sc += part[2 * i + 1];
        }
    } else if (threadIdx.x == 0) {
        sp = part[0]; sc = part[1];
    }
#pragma unroll
    for (int off = 32; off > 0; off >>= 1) {
        sp += __shfl_down(sp, off, 64);
        sc += __shfl_down(sc, off, 64);
    }
    __shared__ double lsp[4], lsc[4];
    const int wave = threadIdx.x >> 6, lane = threadIdx.x & 63;
    if (lane == 0) { lsp[wave] = sp; lsc[wave] = sc; }
    __syncthreads();
    if (threadIdx.x == 0) {
        double tp = lsp[0] + lsp[1] + lsp[2] + lsp[3];
        double tc = lsc[0] + lsc[1] + lsc[2] + lsc[3];
        out[0] = (float)(tp / (tc + 1e-8));
    }
}

extern "C" void kernel_launch(void* const* d_in, const int* in_sizes, int n_in,
                              void* d_out, int out_size, void* d_ws, size_t ws_size,
                              hipStream_t stream) {
    const float* phi = (const float*)d_in[0];
    float* out = (float*)d_out;
    double* acc = (double*)d_ws;

    const int use_partials = (ws_size >= (size_t)(2 * NBLOCKS) * sizeof(double)) ? 1 : 0;
    if (!use_partials) {
        hipMemsetAsync(d_ws, 0, 2 * sizeof(double), stream);
    }

    curv_main<<<NBLOCKS, 256, 0, stream>>>(phi, acc, use_partials);
    curv_reduce<<<1, 256, 0, stream>>>(acc, NBLOCKS, use_partials, out);
}